// Round 8
// baseline (498.149 us; speedup 1.0000x reference)
//
#include <hip/hip_runtime.h>
#include <hip/hip_bf16.h>
#include <math.h>

// ---------------------------------------------------------------------------
// GCN: 3x GCNConv(128->128) + fused (Wp1@Wp2) head + log_softmax.
// Round 8: barrier-free fused aggregate+GEMM. Each 64-lane wave processes its
// 16 nodes SEQUENTIALLY (64 lanes x 4B = one 256B row per edge load): wave
// time = sum(d_i) (+-6%) instead of max(d_i) (+35% barrier makespan that cost
// rounds 6/7 their gather BW). Wave owns its whole 16-row MFMA A-tile ->
// zero __syncthreads. CH reverted to 8192 (2048 quadrupled hist-merge atomics).
// ---------------------------------------------------------------------------

#define DH 128    // feature dim (D == H == 128)
#define NC 40     // classes
#define BN 256    // nodes per bucket
#define MAXNB 512 // max buckets (N <= 131072)
#define CH 8192   // edges per scatter block
#define ECAP 6144 // LDS edge capacity in bucket_csr
#define SP 136    // LDS row stride (elems): 128 + 8 pad (breaks 16-way conflict)

typedef __attribute__((ext_vector_type(8))) short bf16x8;
typedef __attribute__((ext_vector_type(4))) float f32x4;

__device__ __forceinline__ unsigned short f2bf(float f) {
    unsigned u = __float_as_uint(f);
    unsigned r = (u + 0x7fffu + ((u >> 16) & 1u)) >> 16;   // RNE
    return (unsigned short)r;
}
__device__ __forceinline__ unsigned pack2(float lo, float hi) {
    return (unsigned)f2bf(lo) | ((unsigned)f2bf(hi) << 16);
}

// ---------------- bucket-level histogram (LDS, then coalesced merge) --------

__global__ __launch_bounds__(256) void bucket_hist(const int* __restrict__ dst, int E,
                                                   unsigned* __restrict__ bcnt) {
    __shared__ unsigned h[MAXNB];
    int tid = threadIdx.x;
    for (int i = tid; i < MAXNB; i += 256) h[i] = 0;
    __syncthreads();
    int e0 = blockIdx.x * CH;
    int e1 = min(e0 + CH, E);
    for (int i = e0 + tid; i < e1; i += 256)
        atomicAdd(&h[dst[i] >> 8], 1u);
    __syncthreads();
    for (int i = tid; i < MAXNB; i += 256)
        if (h[i]) atomicAdd(&bcnt[i], h[i]);
}

__global__ __launch_bounds__(256) void bucket_alloc(const unsigned* __restrict__ bcnt,
                                                    unsigned* __restrict__ bbase,
                                                    unsigned* __restrict__ bpos,
                                                    unsigned* __restrict__ cursor, int NB) {
    int i = blockIdx.x * 256 + threadIdx.x;
    if (i < NB) {
        unsigned c = bcnt[i];
        unsigned o = atomicAdd(cursor, c);
        bbase[i] = o;
        bpos[i] = o;
    }
}

__global__ __launch_bounds__(256) void bucket_scatter(const int* __restrict__ src,
                                                      const int* __restrict__ dst, int E,
                                                      unsigned* __restrict__ bpos,
                                                      unsigned* __restrict__ ebuf) {
    __shared__ unsigned hist[MAXNB];
    __shared__ unsigned lbase[MAXNB];
    __shared__ unsigned gbase[MAXNB];
    __shared__ unsigned cur[MAXNB];
    __shared__ unsigned sorted[CH];
    __shared__ unsigned short sbkt[CH];
    __shared__ unsigned total;

    int tid = threadIdx.x;
    int e0 = blockIdx.x * CH;
    int nE = min(CH, E - e0);

    for (int i = tid; i < MAXNB; i += 256) { hist[i] = 0; cur[i] = 0; }
    if (tid == 0) total = 0;
    __syncthreads();

    for (int i = tid; i < nE; i += 256)
        atomicAdd(&hist[dst[e0 + i] >> 8], 1u);
    __syncthreads();

    for (int i = tid; i < MAXNB; i += 256) {
        unsigned h = hist[i];
        lbase[i] = h ? atomicAdd(&total, h) : 0u;
        gbase[i] = h ? atomicAdd(&bpos[i], h) : 0u;
    }
    __syncthreads();

    for (int i = tid; i < nE; i += 256) {
        int s = src[e0 + i];
        int d = dst[e0 + i];
        unsigned b = (unsigned)d >> 8;
        unsigned r = atomicAdd(&cur[b], 1u);
        unsigned p = lbase[b] + r;
        sorted[p] = ((unsigned)s << 8) | ((unsigned)d & 255u);
        sbkt[p] = (unsigned short)b;
    }
    __syncthreads();

    for (int p = tid; p < nE; p += 256) {
        unsigned b = sbkt[p];
        ebuf[gbase[b] + (p - lbase[b])] = sorted[p];
    }
}

__global__ __launch_bounds__(256) void bucket_csr(const unsigned* __restrict__ ebuf,
                                                  const unsigned* __restrict__ bbase,
                                                  const unsigned* __restrict__ bcnt,
                                                  unsigned* __restrict__ off,
                                                  unsigned* __restrict__ cnt,
                                                  float* __restrict__ nrm,
                                                  int* __restrict__ csr, int N) {
    __shared__ unsigned h[BN];
    __shared__ unsigned nb[BN];
    __shared__ unsigned ncur[BN];
    __shared__ int lcsr[ECAP];
    __shared__ unsigned tot;

    int b = blockIdx.x;
    int tid = threadIdx.x;
    unsigned ebase = bbase[b];
    unsigned ecnt = bcnt[b];

    h[tid] = 0;
    if (tid == 0) tot = 0;
    __syncthreads();

    for (unsigned i = tid; i < ecnt; i += 256)
        atomicAdd(&h[ebuf[ebase + i] & 255u], 1u);
    __syncthreads();

    unsigned myh = h[tid];
    unsigned mybase = myh ? atomicAdd(&tot, myh) : 0u;
    nb[tid] = mybase;
    ncur[tid] = 0;
    int node = b * BN + tid;
    if (node < N) {
        off[node] = ebase + mybase;
        cnt[node] = myh;
        nrm[node] = rsqrtf((float)myh + 1.0f);
    }
    __syncthreads();

    if (ecnt <= ECAP) {
        for (unsigned i = tid; i < ecnt; i += 256) {
            unsigned v = ebuf[ebase + i];
            unsigned nl = v & 255u;
            unsigned r = atomicAdd(&ncur[nl], 1u);
            lcsr[nb[nl] + r] = (int)(v >> 8);
        }
        __syncthreads();
        for (unsigned i = tid; i < ecnt; i += 256)
            csr[ebase + i] = lcsr[i];
    } else {
        for (unsigned i = tid; i < ecnt; i += 256) {
            unsigned v = ebuf[ebase + i];
            unsigned nl = v & 255u;
            unsigned r = atomicAdd(&ncur[nl], 1u);
            csr[ebase + nb[nl] + r] = (int)(v >> 8);
        }
    }
}

// ---------------- weight prep: Wt (3 layers, transposed bf16) + fused head --

__global__ __launch_bounds__(256) void prep_w(const float* __restrict__ W1,
                                              const float* __restrict__ W2,
                                              const float* __restrict__ W3,
                                              const float* __restrict__ Wp1,
                                              const float* __restrict__ bp1,
                                              const float* __restrict__ Wp2,
                                              const float* __restrict__ bp2,
                                              unsigned short* __restrict__ Wt,
                                              unsigned short* __restrict__ Wft,
                                              float* __restrict__ bfh) {
    int id = blockIdx.x * 256 + threadIdx.x;
    if (id < 3 * DH * DH) {
        int l = id >> 14, r = id & (DH * DH - 1);
        int k = r >> 7, n = r & 127;
        const float* W = (l == 0) ? W1 : (l == 1) ? W2 : W3;
        Wt[l * DH * DH + n * DH + k] = f2bf(W[k * DH + n]);
    } else if (id < 3 * DH * DH + 48 * DH) {
        int o = id - 3 * DH * DH;
        int c = o >> 7, k = o & 127;
        float acc = 0.f;
        if (c < NC)
            for (int j = 0; j < DH; ++j) acc += Wp1[k * DH + j] * Wp2[j * NC + c];
        Wft[c * DH + k] = f2bf(acc);
    } else if (id < 3 * DH * DH + 48 * DH + 48) {
        int c = id - 3 * DH * DH - 48 * DH;
        float acc = 0.f;
        if (c < NC) {
            acc = bp2[c];
            for (int j = 0; j < DH; ++j) acc += bp1[j] * Wp2[j * NC + c];
        }
        bfh[c] = acc;
    }
}

// ---------------- layer-1 MFMA GEMM: Ab = bf16(nrm * (x_f32 @ W1)) ----------

__global__ __launch_bounds__(256) void gemm_mfma_f32(const float* __restrict__ X,
                                                     const unsigned short* __restrict__ Wt,
                                                     const float* __restrict__ nrm,
                                                     unsigned short* __restrict__ outb,
                                                     int nrows) {
    const int tid = threadIdx.x;
    const int wave = tid >> 6;
    const int lane = tid & 63;
    const int m = lane & 15;
    const int quad = lane >> 4;
    const int rbase = blockIdx.x * 128 + wave * 32;

    union U8 { bf16x8 v; unsigned u[4]; };

    f32x4 acc[2][8];
#pragma unroll
    for (int rt = 0; rt < 2; ++rt)
#pragma unroll
        for (int ct = 0; ct < 8; ++ct) acc[rt][ct] = (f32x4){0.f, 0.f, 0.f, 0.f};

#pragma unroll
    for (int kt = 0; kt < 4; ++kt) {
        const int kof = kt * 32 + quad * 8;
        bf16x8 a[2], b[8];
#pragma unroll
        for (int rt = 0; rt < 2; ++rt) {
            int r = rbase + rt * 16 + m;
            r = (r < nrows) ? r : (nrows - 1);
            const float* p = X + (size_t)r * DH + kof;
            float4 u0 = *(const float4*)p;
            float4 u1 = *(const float4*)(p + 4);
            U8 t;
            t.u[0] = pack2(u0.x, u0.y);
            t.u[1] = pack2(u0.z, u0.w);
            t.u[2] = pack2(u1.x, u1.y);
            t.u[3] = pack2(u1.z, u1.w);
            a[rt] = t.v;
        }
#pragma unroll
        for (int ct = 0; ct < 8; ++ct)
            b[ct] = *(const bf16x8*)(Wt + (ct * 16 + m) * DH + kof);
#pragma unroll
        for (int rt = 0; rt < 2; ++rt)
#pragma unroll
            for (int ct = 0; ct < 8; ++ct)
                acc[rt][ct] = __builtin_amdgcn_mfma_f32_16x16x32_bf16(a[rt], b[ct], acc[rt][ct], 0, 0, 0);
    }

#pragma unroll
    for (int rt = 0; rt < 2; ++rt)
#pragma unroll
        for (int reg = 0; reg < 4; ++reg) {
            int r = rbase + rt * 16 + quad * 4 + reg;
            if (r < nrows) {
                float s = nrm[r];
#pragma unroll
                for (int ct = 0; ct < 8; ++ct)
                    outb[(size_t)r * DH + ct * 16 + m] = f2bf(acc[rt][ct][reg] * s);
            }
        }
}

// ---------------- per-wave sequential gather of 16 nodes --------------------
// All 64 lanes on ONE node's edge list at a time: lane l holds cols 2l,2l+1
// (one dword = one 256B row load per edge, wave-uniform edge index -> scalar
// csr loads). Wave work = sum(d_i) -> near-perfect balance, no barrier.
// z = relu(nrm*(sum+self)+bias) -> bf16 into this wave's sA[16][SP].

__device__ __forceinline__ void gather16(const unsigned* __restrict__ Abf,
                                         const int* __restrict__ csr,
                                         const unsigned* __restrict__ off,
                                         const unsigned* __restrict__ cnt,
                                         const float* __restrict__ nrm,
                                         const float* __restrict__ bias,
                                         unsigned short (*sA)[SP], int nb, int N) {
    const int l = threadIdx.x & 63;
    const float b0 = bias[l * 2];
    const float b1 = bias[l * 2 + 1];

    for (int g = 0; g < 16; ++g) {
        int node = nb + g;
        if (node >= N) break;                      // wave-uniform
        unsigned o = off[node];
        unsigned d = cnt[node];

        unsigned v = Abf[(size_t)node * 64 + l];   // self term
        float a0 = __uint_as_float(v << 16);
        float a1 = __uint_as_float(v & 0xffff0000u);

        unsigned e = 0;
        for (; e + 8 <= d; e += 8) {
            int s0 = csr[o + e + 0];
            int s1 = csr[o + e + 1];
            int s2 = csr[o + e + 2];
            int s3 = csr[o + e + 3];
            int s4 = csr[o + e + 4];
            int s5 = csr[o + e + 5];
            int s6 = csr[o + e + 6];
            int s7 = csr[o + e + 7];
            unsigned v0 = Abf[(size_t)s0 * 64 + l];
            unsigned v1 = Abf[(size_t)s1 * 64 + l];
            unsigned v2 = Abf[(size_t)s2 * 64 + l];
            unsigned v3 = Abf[(size_t)s3 * 64 + l];
            unsigned v4 = Abf[(size_t)s4 * 64 + l];
            unsigned v5 = Abf[(size_t)s5 * 64 + l];
            unsigned v6 = Abf[(size_t)s6 * 64 + l];
            unsigned v7 = Abf[(size_t)s7 * 64 + l];
            a0 += __uint_as_float(v0 << 16); a1 += __uint_as_float(v0 & 0xffff0000u);
            a0 += __uint_as_float(v1 << 16); a1 += __uint_as_float(v1 & 0xffff0000u);
            a0 += __uint_as_float(v2 << 16); a1 += __uint_as_float(v2 & 0xffff0000u);
            a0 += __uint_as_float(v3 << 16); a1 += __uint_as_float(v3 & 0xffff0000u);
            a0 += __uint_as_float(v4 << 16); a1 += __uint_as_float(v4 & 0xffff0000u);
            a0 += __uint_as_float(v5 << 16); a1 += __uint_as_float(v5 & 0xffff0000u);
            a0 += __uint_as_float(v6 << 16); a1 += __uint_as_float(v6 & 0xffff0000u);
            a0 += __uint_as_float(v7 << 16); a1 += __uint_as_float(v7 & 0xffff0000u);
        }
        for (; e < d; ++e) {
            int s = csr[o + e];
            unsigned vv = Abf[(size_t)s * 64 + l];
            a0 += __uint_as_float(vv << 16);
            a1 += __uint_as_float(vv & 0xffff0000u);
        }

        float nm = nrm[node];
        float r0 = fmaxf(a0 * nm + b0, 0.f);
        float r1 = fmaxf(a1 * nm + b1, 0.f);
        ((unsigned*)&sA[g][0])[l] = pack2(r0, r1);
    }
}

// ---------------- fused: aggregate + next-layer GEMM (no barriers) ----------
// 256 threads = 4 independent waves; wave w owns nodes [blk*64+w*16, +16) and
// its own sA tile. After gather: 8 col-tiles of 16x16x32 MFMA vs Wt.

__global__ __launch_bounds__(256) void agg_gemm(const unsigned* __restrict__ Abf,
                                                const int* __restrict__ csr,
                                                const unsigned* __restrict__ off,
                                                const unsigned* __restrict__ cnt,
                                                const float* __restrict__ nrm,
                                                const float* __restrict__ bias,
                                                const unsigned short* __restrict__ Wt,
                                                unsigned short* __restrict__ outb, int N) {
    __shared__ unsigned short sA[4][16][SP];
    const int wave = threadIdx.x >> 6;
    const int nb = blockIdx.x * 64 + wave * 16;
    if (nb >= N) return;

    gather16(Abf, csr, off, cnt, nrm, bias, sA[wave], nb, N);

    const int l64 = threadIdx.x & 63;
    const int m = l64 & 15;
    const int quad = l64 >> 4;

    bf16x8 a[4];
#pragma unroll
    for (int kt = 0; kt < 4; ++kt)
        a[kt] = *(const bf16x8*)&sA[wave][m][kt * 32 + quad * 8];

#pragma unroll
    for (int ct = 0; ct < 8; ++ct) {
        f32x4 acc = (f32x4){0.f, 0.f, 0.f, 0.f};
#pragma unroll
        for (int kt = 0; kt < 4; ++kt) {
            bf16x8 b = *(const bf16x8*)(Wt + (ct * 16 + m) * DH + kt * 32 + quad * 8);
            acc = __builtin_amdgcn_mfma_f32_16x16x32_bf16(a[kt], b, acc, 0, 0, 0);
        }
#pragma unroll
        for (int reg = 0; reg < 4; ++reg) {
            int r = nb + quad * 4 + reg;
            if (r < N)
                outb[(size_t)r * DH + ct * 16 + m] = f2bf(acc[reg] * nrm[r]);
        }
    }
}

// ---------------- fused: aggregate + head GEMM + log_softmax (no barriers) --

__global__ __launch_bounds__(256) void agg_head(const unsigned* __restrict__ Abf,
                                                const int* __restrict__ csr,
                                                const unsigned* __restrict__ off,
                                                const unsigned* __restrict__ cnt,
                                                const float* __restrict__ nrm,
                                                const float* __restrict__ bias,
                                                const unsigned short* __restrict__ Wft,
                                                const float* __restrict__ bfh,
                                                float* __restrict__ out, int N) {
    __shared__ unsigned short sA[4][16][SP];
    const int wave = threadIdx.x >> 6;
    const int nb = blockIdx.x * 64 + wave * 16;
    if (nb >= N) return;

    gather16(Abf, csr, off, cnt, nrm, bias, sA[wave], nb, N);

    const int l64 = threadIdx.x & 63;
    const int m = l64 & 15;
    const int quad = l64 >> 4;

    bf16x8 a[4];
#pragma unroll
    for (int kt = 0; kt < 4; ++kt)
        a[kt] = *(const bf16x8*)&sA[wave][m][kt * 32 + quad * 8];

    f32x4 acc[3];
#pragma unroll
    for (int ct = 0; ct < 3; ++ct) {
        acc[ct] = (f32x4){0.f, 0.f, 0.f, 0.f};
#pragma unroll
        for (int kt = 0; kt < 4; ++kt) {
            bf16x8 b = *(const bf16x8*)(Wft + (ct * 16 + m) * DH + kt * 32 + quad * 8);
            acc[ct] = __builtin_amdgcn_mfma_f32_16x16x32_bf16(a[kt], b, acc[ct], 0, 0, 0);
        }
    }

    float bias0 = bfh[m];
    float bias1 = bfh[16 + m];
    float bias2 = bfh[32 + m];

#pragma unroll
    for (int reg = 0; reg < 4; ++reg) {
        float v0 = acc[0][reg] + bias0;
        float v1 = acc[1][reg] + bias1;
        float v2 = (m < 8) ? (acc[2][reg] + bias2) : -1e30f;
        float mx = fmaxf(fmaxf(v0, v1), v2);
#pragma unroll
        for (int dlt = 1; dlt < 16; dlt <<= 1) mx = fmaxf(mx, __shfl_xor(mx, dlt));
        float s = __expf(v0 - mx) + __expf(v1 - mx) + ((m < 8) ? __expf(v2 - mx) : 0.f);
#pragma unroll
        for (int dlt = 1; dlt < 16; dlt <<= 1) s += __shfl_xor(s, dlt);
        float ls = mx + __logf(s);
        int r = nb + quad * 4 + reg;
        if (r < N) {
            out[(size_t)r * NC + m] = v0 - ls;
            out[(size_t)r * NC + 16 + m] = v1 - ls;
            if (m < 8) out[(size_t)r * NC + 32 + m] = v2 - ls;
        }
    }
}

// ---------------------------------------------------------------------------

extern "C" void kernel_launch(void* const* d_in, const int* in_sizes, int n_in,
                              void* d_out, int out_size, void* d_ws, size_t ws_size,
                              hipStream_t stream) {
    const float* x   = (const float*)d_in[0];
    const int*   ei  = (const int*)d_in[1];
    const float* W1  = (const float*)d_in[2];
    const float* b1  = (const float*)d_in[3];
    const float* W2  = (const float*)d_in[4];
    const float* b2  = (const float*)d_in[5];
    const float* W3  = (const float*)d_in[6];
    const float* b3  = (const float*)d_in[7];
    const float* Wp1 = (const float*)d_in[8];
    const float* bp1 = (const float*)d_in[9];
    const float* Wp2 = (const float*)d_in[10];
    const float* bp2 = (const float*)d_in[11];
    float* out = (float*)d_out;

    const int N = in_sizes[0] / DH;
    const int E = in_sizes[1] / 2;
    const int* src = ei;
    const int* dst = ei + E;
    const int NB = (N + BN - 1) / BN;

    // workspace carve (all 16B aligned)
    char* w = (char*)d_ws;
    unsigned short* Ab  = (unsigned short*)w; w += (size_t)N * DH * 2;
    unsigned short* Bb  = (unsigned short*)w; w += (size_t)N * DH * 2;
    int*      csr    = (int*)w;      w += (size_t)E * 4;
    unsigned* ebuf   = (unsigned*)w; w += (size_t)E * 4;
    unsigned* bcnt   = (unsigned*)w; w += MAXNB * 4;
    unsigned* cursor = (unsigned*)w; w += 16;
    unsigned* bbase  = (unsigned*)w; w += MAXNB * 4;
    unsigned* bpos   = (unsigned*)w; w += MAXNB * 4;
    unsigned* off    = (unsigned*)w; w += (size_t)N * 4;
    unsigned* cnt    = (unsigned*)w; w += (size_t)N * 4;
    float*    nrm    = (float*)w;    w += (size_t)N * 4;
    unsigned short* Wt  = (unsigned short*)w; w += 3 * DH * DH * 2;
    unsigned short* Wft = (unsigned short*)w; w += 48 * DH * 2;
    float*    bfh    = (float*)w;    w += 64 * 4;

    const int gC = (E + CH - 1) / CH;

    hipMemsetAsync(bcnt, 0, MAXNB * 4 + 16, stream);   // bcnt + cursor
    bucket_hist   <<<gC, 256, 0, stream>>>(dst, E, bcnt);
    bucket_alloc  <<<(NB + 255) / 256, 256, 0, stream>>>(bcnt, bbase, bpos, cursor, NB);
    bucket_scatter<<<gC, 256, 0, stream>>>(src, dst, E, bpos, ebuf);
    bucket_csr    <<<NB, 256, 0, stream>>>(ebuf, bbase, bcnt, off, cnt, nrm, csr, N);
    prep_w<<<(3 * DH * DH + 48 * DH + 48 + 255) / 256, 256, 0, stream>>>(
        W1, W2, W3, Wp1, bp1, Wp2, bp2, Wt, Wft, bfh);

    const int gG = (N + 127) / 128;
    const int gF = (N + 63) / 64;

    gemm_mfma_f32<<<gG, 256, 0, stream>>>(x, Wt, nrm, Ab, N);
    agg_gemm<<<gF, 256, 0, stream>>>((const unsigned*)Ab, csr, off, cnt, nrm, b1,
                                     Wt + DH * DH, Bb, N);
    agg_gemm<<<gF, 256, 0, stream>>>((const unsigned*)Bb, csr, off, cnt, nrm, b2,
                                     Wt + 2 * DH * DH, Ab, N);
    agg_head<<<gF, 256, 0, stream>>>((const unsigned*)Ab, csr, off, cnt, nrm, b3,
                                     Wft, bfh, out, N);
}

// Round 9
// 454.087 us; speedup vs baseline: 1.0970x; 1.0970x over previous
//
#include <hip/hip_runtime.h>
#include <hip/hip_bf16.h>
#include <math.h>

// ---------------------------------------------------------------------------
// GCN: 3x GCNConv(128->128) + fused (Wp1@Wp2) head + log_softmax.
// Round 9: fused aggregate+GEMM with MLP-preserving balanced gather.
// R4's load shape (16 lanes/node, uint4 = 64 B/lane in flight) was the BW
// winner (3.59 TB/s); R8's dword sequential gather killed MLP (2.11 TB/s).
// Here: each wave = 4 groups x 16 lanes; group gathers 4 sequential nodes
// (makespan +13% vs +35% for max-of-16) -> wave owns its 16-row MFMA tile,
// zero __syncthreads. Summation order unchanged -> bit-identical output.
// ---------------------------------------------------------------------------

#define DH 128    // feature dim (D == H == 128)
#define NC 40     // classes
#define BN 256    // nodes per bucket
#define MAXNB 512 // max buckets (N <= 131072)
#define CH 8192   // edges per scatter block
#define ECAP 6144 // LDS edge capacity in bucket_csr
#define SP 136    // LDS row stride (elems): 128 + 8 pad

typedef __attribute__((ext_vector_type(8))) short bf16x8;
typedef __attribute__((ext_vector_type(4))) float f32x4;

__device__ __forceinline__ unsigned short f2bf(float f) {
    unsigned u = __float_as_uint(f);
    unsigned r = (u + 0x7fffu + ((u >> 16) & 1u)) >> 16;   // RNE
    return (unsigned short)r;
}
__device__ __forceinline__ unsigned pack2(float lo, float hi) {
    return (unsigned)f2bf(lo) | ((unsigned)f2bf(hi) << 16);
}

// ---------------- bucket-level histogram (LDS, then coalesced merge) --------

__global__ __launch_bounds__(256) void bucket_hist(const int* __restrict__ dst, int E,
                                                   unsigned* __restrict__ bcnt) {
    __shared__ unsigned h[MAXNB];
    int tid = threadIdx.x;
    for (int i = tid; i < MAXNB; i += 256) h[i] = 0;
    __syncthreads();
    int e0 = blockIdx.x * CH;
    int e1 = min(e0 + CH, E);
    for (int i = e0 + tid; i < e1; i += 256)
        atomicAdd(&h[dst[i] >> 8], 1u);
    __syncthreads();
    for (int i = tid; i < MAXNB; i += 256)
        if (h[i]) atomicAdd(&bcnt[i], h[i]);
}

__global__ __launch_bounds__(256) void bucket_alloc(const unsigned* __restrict__ bcnt,
                                                    unsigned* __restrict__ bbase,
                                                    unsigned* __restrict__ bpos,
                                                    unsigned* __restrict__ cursor, int NB) {
    int i = blockIdx.x * 256 + threadIdx.x;
    if (i < NB) {
        unsigned c = bcnt[i];
        unsigned o = atomicAdd(cursor, c);
        bbase[i] = o;
        bpos[i] = o;
    }
}

__global__ __launch_bounds__(256) void bucket_scatter(const int* __restrict__ src,
                                                      const int* __restrict__ dst, int E,
                                                      unsigned* __restrict__ bpos,
                                                      unsigned* __restrict__ ebuf) {
    __shared__ unsigned hist[MAXNB];
    __shared__ unsigned lbase[MAXNB];
    __shared__ unsigned gbase[MAXNB];
    __shared__ unsigned cur[MAXNB];
    __shared__ unsigned sorted[CH];
    __shared__ unsigned short sbkt[CH];
    __shared__ unsigned total;

    int tid = threadIdx.x;
    int e0 = blockIdx.x * CH;
    int nE = min(CH, E - e0);

    for (int i = tid; i < MAXNB; i += 256) { hist[i] = 0; cur[i] = 0; }
    if (tid == 0) total = 0;
    __syncthreads();

    for (int i = tid; i < nE; i += 256)
        atomicAdd(&hist[dst[e0 + i] >> 8], 1u);
    __syncthreads();

    for (int i = tid; i < MAXNB; i += 256) {
        unsigned h = hist[i];
        lbase[i] = h ? atomicAdd(&total, h) : 0u;
        gbase[i] = h ? atomicAdd(&bpos[i], h) : 0u;
    }
    __syncthreads();

    for (int i = tid; i < nE; i += 256) {
        int s = src[e0 + i];
        int d = dst[e0 + i];
        unsigned b = (unsigned)d >> 8;
        unsigned r = atomicAdd(&cur[b], 1u);
        unsigned p = lbase[b] + r;
        sorted[p] = ((unsigned)s << 8) | ((unsigned)d & 255u);
        sbkt[p] = (unsigned short)b;
    }
    __syncthreads();

    for (int p = tid; p < nE; p += 256) {
        unsigned b = sbkt[p];
        ebuf[gbase[b] + (p - lbase[b])] = sorted[p];
    }
}

__global__ __launch_bounds__(256) void bucket_csr(const unsigned* __restrict__ ebuf,
                                                  const unsigned* __restrict__ bbase,
                                                  const unsigned* __restrict__ bcnt,
                                                  unsigned* __restrict__ off,
                                                  unsigned* __restrict__ cnt,
                                                  float* __restrict__ nrm,
                                                  int* __restrict__ csr, int N) {
    __shared__ unsigned h[BN];
    __shared__ unsigned nb[BN];
    __shared__ unsigned ncur[BN];
    __shared__ int lcsr[ECAP];
    __shared__ unsigned tot;

    int b = blockIdx.x;
    int tid = threadIdx.x;
    unsigned ebase = bbase[b];
    unsigned ecnt = bcnt[b];

    h[tid] = 0;
    if (tid == 0) tot = 0;
    __syncthreads();

    for (unsigned i = tid; i < ecnt; i += 256)
        atomicAdd(&h[ebuf[ebase + i] & 255u], 1u);
    __syncthreads();

    unsigned myh = h[tid];
    unsigned mybase = myh ? atomicAdd(&tot, myh) : 0u;
    nb[tid] = mybase;
    ncur[tid] = 0;
    int node = b * BN + tid;
    if (node < N) {
        off[node] = ebase + mybase;
        cnt[node] = myh;
        nrm[node] = rsqrtf((float)myh + 1.0f);
    }
    __syncthreads();

    if (ecnt <= ECAP) {
        for (unsigned i = tid; i < ecnt; i += 256) {
            unsigned v = ebuf[ebase + i];
            unsigned nl = v & 255u;
            unsigned r = atomicAdd(&ncur[nl], 1u);
            lcsr[nb[nl] + r] = (int)(v >> 8);
        }
        __syncthreads();
        for (unsigned i = tid; i < ecnt; i += 256)
            csr[ebase + i] = lcsr[i];
    } else {
        for (unsigned i = tid; i < ecnt; i += 256) {
            unsigned v = ebuf[ebase + i];
            unsigned nl = v & 255u;
            unsigned r = atomicAdd(&ncur[nl], 1u);
            csr[ebase + nb[nl] + r] = (int)(v >> 8);
        }
    }
}

// ---------------- weight prep: Wt (3 layers, transposed bf16) + fused head --

__global__ __launch_bounds__(256) void prep_w(const float* __restrict__ W1,
                                              const float* __restrict__ W2,
                                              const float* __restrict__ W3,
                                              const float* __restrict__ Wp1,
                                              const float* __restrict__ bp1,
                                              const float* __restrict__ Wp2,
                                              const float* __restrict__ bp2,
                                              unsigned short* __restrict__ Wt,
                                              unsigned short* __restrict__ Wft,
                                              float* __restrict__ bfh) {
    int id = blockIdx.x * 256 + threadIdx.x;
    if (id < 3 * DH * DH) {
        int l = id >> 14, r = id & (DH * DH - 1);
        int k = r >> 7, n = r & 127;
        const float* W = (l == 0) ? W1 : (l == 1) ? W2 : W3;
        Wt[l * DH * DH + n * DH + k] = f2bf(W[k * DH + n]);
    } else if (id < 3 * DH * DH + 48 * DH) {
        int o = id - 3 * DH * DH;
        int c = o >> 7, k = o & 127;
        float acc = 0.f;
        if (c < NC)
            for (int j = 0; j < DH; ++j) acc += Wp1[k * DH + j] * Wp2[j * NC + c];
        Wft[c * DH + k] = f2bf(acc);
    } else if (id < 3 * DH * DH + 48 * DH + 48) {
        int c = id - 3 * DH * DH - 48 * DH;
        float acc = 0.f;
        if (c < NC) {
            acc = bp2[c];
            for (int j = 0; j < DH; ++j) acc += bp1[j] * Wp2[j * NC + c];
        }
        bfh[c] = acc;
    }
}

// ---------------- layer-1 MFMA GEMM: Ab = bf16(nrm * (x_f32 @ W1)) ----------

__global__ __launch_bounds__(256) void gemm_mfma_f32(const float* __restrict__ X,
                                                     const unsigned short* __restrict__ Wt,
                                                     const float* __restrict__ nrm,
                                                     unsigned short* __restrict__ outb,
                                                     int nrows) {
    const int tid = threadIdx.x;
    const int wave = tid >> 6;
    const int lane = tid & 63;
    const int m = lane & 15;
    const int quad = lane >> 4;
    const int rbase = blockIdx.x * 128 + wave * 32;

    union U8 { bf16x8 v; unsigned u[4]; };

    f32x4 acc[2][8];
#pragma unroll
    for (int rt = 0; rt < 2; ++rt)
#pragma unroll
        for (int ct = 0; ct < 8; ++ct) acc[rt][ct] = (f32x4){0.f, 0.f, 0.f, 0.f};

#pragma unroll
    for (int kt = 0; kt < 4; ++kt) {
        const int kof = kt * 32 + quad * 8;
        bf16x8 a[2], b[8];
#pragma unroll
        for (int rt = 0; rt < 2; ++rt) {
            int r = rbase + rt * 16 + m;
            r = (r < nrows) ? r : (nrows - 1);
            const float* p = X + (size_t)r * DH + kof;
            float4 u0 = *(const float4*)p;
            float4 u1 = *(const float4*)(p + 4);
            U8 t;
            t.u[0] = pack2(u0.x, u0.y);
            t.u[1] = pack2(u0.z, u0.w);
            t.u[2] = pack2(u1.x, u1.y);
            t.u[3] = pack2(u1.z, u1.w);
            a[rt] = t.v;
        }
#pragma unroll
        for (int ct = 0; ct < 8; ++ct)
            b[ct] = *(const bf16x8*)(Wt + (ct * 16 + m) * DH + kof);
#pragma unroll
        for (int rt = 0; rt < 2; ++rt)
#pragma unroll
            for (int ct = 0; ct < 8; ++ct)
                acc[rt][ct] = __builtin_amdgcn_mfma_f32_16x16x32_bf16(a[rt], b[ct], acc[rt][ct], 0, 0, 0);
    }

#pragma unroll
    for (int rt = 0; rt < 2; ++rt)
#pragma unroll
        for (int reg = 0; reg < 4; ++reg) {
            int r = rbase + rt * 16 + quad * 4 + reg;
            if (r < nrows) {
                float s = nrm[r];
#pragma unroll
                for (int ct = 0; ct < 8; ++ct)
                    outb[(size_t)r * DH + ct * 16 + m] = f2bf(acc[rt][ct][reg] * s);
            }
        }
}

// ---------------- per-wave gather: 4 groups x 16 lanes, 4 nodes each --------
// Group grp handles nodes nb+grp*4 .. +3 sequentially; 16 lanes x uint4
// (8 bf16 cols) per node row, 4-deep edge unroll = 64 B/lane in flight.
// z = relu(nrm*(sum+self)+bias) -> bf16 into the wave's sA[16][SP]. No barrier.

__device__ __forceinline__ void bf8_add(float* acc, uint4 v) {
    acc[0] += __uint_as_float(v.x << 16);
    acc[1] += __uint_as_float(v.x & 0xffff0000u);
    acc[2] += __uint_as_float(v.y << 16);
    acc[3] += __uint_as_float(v.y & 0xffff0000u);
    acc[4] += __uint_as_float(v.z << 16);
    acc[5] += __uint_as_float(v.z & 0xffff0000u);
    acc[6] += __uint_as_float(v.w << 16);
    acc[7] += __uint_as_float(v.w & 0xffff0000u);
}

__device__ __forceinline__ void gather_w4(const uint4* __restrict__ Abf,
                                          const int* __restrict__ csr,
                                          const unsigned* __restrict__ off,
                                          const unsigned* __restrict__ cnt,
                                          const float* __restrict__ nrm,
                                          const float* __restrict__ bias,
                                          unsigned short (*sA)[SP], int nb, int N) {
    const int l64 = threadIdx.x & 63;
    const int grp = l64 >> 4;        // 0..3
    const int lane = l64 & 15;       // col lane (8 bf16 cols)
    const float4 b0 = *(const float4*)(bias + lane * 8);
    const float4 b1 = *(const float4*)(bias + lane * 8 + 4);

#pragma unroll
    for (int j = 0; j < 4; ++j) {
        const int g = grp * 4 + j;
        const int node = nb + g;
        if (node >= N) break;

        float acc[8];
        {
            uint4 v = Abf[(size_t)node * 16 + lane];   // self term
            acc[0] = __uint_as_float(v.x << 16);
            acc[1] = __uint_as_float(v.x & 0xffff0000u);
            acc[2] = __uint_as_float(v.y << 16);
            acc[3] = __uint_as_float(v.y & 0xffff0000u);
            acc[4] = __uint_as_float(v.z << 16);
            acc[5] = __uint_as_float(v.z & 0xffff0000u);
            acc[6] = __uint_as_float(v.w << 16);
            acc[7] = __uint_as_float(v.w & 0xffff0000u);
        }
        unsigned o = off[node];
        unsigned d = cnt[node];

        unsigned e = 0;
        for (; e + 4 <= d; e += 4) {
            int s0 = csr[o + e + 0];
            int s1 = csr[o + e + 1];
            int s2 = csr[o + e + 2];
            int s3 = csr[o + e + 3];
            uint4 v0 = Abf[(size_t)s0 * 16 + lane];
            uint4 v1 = Abf[(size_t)s1 * 16 + lane];
            uint4 v2 = Abf[(size_t)s2 * 16 + lane];
            uint4 v3 = Abf[(size_t)s3 * 16 + lane];
            bf8_add(acc, v0);
            bf8_add(acc, v1);
            bf8_add(acc, v2);
            bf8_add(acc, v3);
        }
        for (; e < d; ++e) {
            int s = csr[o + e];
            uint4 v = Abf[(size_t)s * 16 + lane];
            bf8_add(acc, v);
        }

        float nm = nrm[node];
        unsigned short* p = &sA[g][lane * 8];
        p[0] = f2bf(fmaxf(acc[0] * nm + b0.x, 0.f));
        p[1] = f2bf(fmaxf(acc[1] * nm + b0.y, 0.f));
        p[2] = f2bf(fmaxf(acc[2] * nm + b0.z, 0.f));
        p[3] = f2bf(fmaxf(acc[3] * nm + b0.w, 0.f));
        p[4] = f2bf(fmaxf(acc[4] * nm + b1.x, 0.f));
        p[5] = f2bf(fmaxf(acc[5] * nm + b1.y, 0.f));
        p[6] = f2bf(fmaxf(acc[6] * nm + b1.z, 0.f));
        p[7] = f2bf(fmaxf(acc[7] * nm + b1.w, 0.f));
    }
}

// ---------------- fused: aggregate + next-layer GEMM (no barriers) ----------
// 256 threads = 4 independent waves; wave w owns nodes [blk*64+w*16, +16) and
// its own sA tile. After gather: 8 col-tiles of 16x16x32 MFMA vs Wt.

__global__ __launch_bounds__(256) void agg_gemm(const uint4* __restrict__ Abf,
                                                const int* __restrict__ csr,
                                                const unsigned* __restrict__ off,
                                                const unsigned* __restrict__ cnt,
                                                const float* __restrict__ nrm,
                                                const float* __restrict__ bias,
                                                const unsigned short* __restrict__ Wt,
                                                unsigned short* __restrict__ outb, int N) {
    __shared__ unsigned short sA[4][16][SP];
    const int wave = threadIdx.x >> 6;
    const int nb = blockIdx.x * 64 + wave * 16;
    if (nb >= N) return;

    gather_w4(Abf, csr, off, cnt, nrm, bias, sA[wave], nb, N);

    const int l64 = threadIdx.x & 63;
    const int m = l64 & 15;
    const int quad = l64 >> 4;

    bf16x8 a[4];
#pragma unroll
    for (int kt = 0; kt < 4; ++kt)
        a[kt] = *(const bf16x8*)&sA[wave][m][kt * 32 + quad * 8];

#pragma unroll
    for (int ct = 0; ct < 8; ++ct) {
        f32x4 acc = (f32x4){0.f, 0.f, 0.f, 0.f};
#pragma unroll
        for (int kt = 0; kt < 4; ++kt) {
            bf16x8 b = *(const bf16x8*)(Wt + (ct * 16 + m) * DH + kt * 32 + quad * 8);
            acc = __builtin_amdgcn_mfma_f32_16x16x32_bf16(a[kt], b, acc, 0, 0, 0);
        }
#pragma unroll
        for (int reg = 0; reg < 4; ++reg) {
            int r = nb + quad * 4 + reg;
            if (r < N)
                outb[(size_t)r * DH + ct * 16 + m] = f2bf(acc[reg] * nrm[r]);
        }
    }
}

// ---------------- fused: aggregate + head GEMM + log_softmax (no barriers) --

__global__ __launch_bounds__(256) void agg_head(const uint4* __restrict__ Abf,
                                                const int* __restrict__ csr,
                                                const unsigned* __restrict__ off,
                                                const unsigned* __restrict__ cnt,
                                                const float* __restrict__ nrm,
                                                const float* __restrict__ bias,
                                                const unsigned short* __restrict__ Wft,
                                                const float* __restrict__ bfh,
                                                float* __restrict__ out, int N) {
    __shared__ unsigned short sA[4][16][SP];
    const int wave = threadIdx.x >> 6;
    const int nb = blockIdx.x * 64 + wave * 16;
    if (nb >= N) return;

    gather_w4(Abf, csr, off, cnt, nrm, bias, sA[wave], nb, N);

    const int l64 = threadIdx.x & 63;
    const int m = l64 & 15;
    const int quad = l64 >> 4;

    bf16x8 a[4];
#pragma unroll
    for (int kt = 0; kt < 4; ++kt)
        a[kt] = *(const bf16x8*)&sA[wave][m][kt * 32 + quad * 8];

    f32x4 acc[3];
#pragma unroll
    for (int ct = 0; ct < 3; ++ct) {
        acc[ct] = (f32x4){0.f, 0.f, 0.f, 0.f};
#pragma unroll
        for (int kt = 0; kt < 4; ++kt) {
            bf16x8 b = *(const bf16x8*)(Wft + (ct * 16 + m) * DH + kt * 32 + quad * 8);
            acc[ct] = __builtin_amdgcn_mfma_f32_16x16x32_bf16(a[kt], b, acc[ct], 0, 0, 0);
        }
    }

    float bias0 = bfh[m];
    float bias1 = bfh[16 + m];
    float bias2 = bfh[32 + m];

#pragma unroll
    for (int reg = 0; reg < 4; ++reg) {
        float v0 = acc[0][reg] + bias0;
        float v1 = acc[1][reg] + bias1;
        float v2 = (m < 8) ? (acc[2][reg] + bias2) : -1e30f;
        float mx = fmaxf(fmaxf(v0, v1), v2);
#pragma unroll
        for (int dlt = 1; dlt < 16; dlt <<= 1) mx = fmaxf(mx, __shfl_xor(mx, dlt));
        float s = __expf(v0 - mx) + __expf(v1 - mx) + ((m < 8) ? __expf(v2 - mx) : 0.f);
#pragma unroll
        for (int dlt = 1; dlt < 16; dlt <<= 1) s += __shfl_xor(s, dlt);
        float ls = mx + __logf(s);
        int r = nb + quad * 4 + reg;
        if (r < N) {
            out[(size_t)r * NC + m] = v0 - ls;
            out[(size_t)r * NC + 16 + m] = v1 - ls;
            if (m < 8) out[(size_t)r * NC + 32 + m] = v2 - ls;
        }
    }
}

// ---------------------------------------------------------------------------

extern "C" void kernel_launch(void* const* d_in, const int* in_sizes, int n_in,
                              void* d_out, int out_size, void* d_ws, size_t ws_size,
                              hipStream_t stream) {
    const float* x   = (const float*)d_in[0];
    const int*   ei  = (const int*)d_in[1];
    const float* W1  = (const float*)d_in[2];
    const float* b1  = (const float*)d_in[3];
    const float* W2  = (const float*)d_in[4];
    const float* b2  = (const float*)d_in[5];
    const float* W3  = (const float*)d_in[6];
    const float* b3  = (const float*)d_in[7];
    const float* Wp1 = (const float*)d_in[8];
    const float* bp1 = (const float*)d_in[9];
    const float* Wp2 = (const float*)d_in[10];
    const float* bp2 = (const float*)d_in[11];
    float* out = (float*)d_out;

    const int N = in_sizes[0] / DH;
    const int E = in_sizes[1] / 2;
    const int* src = ei;
    const int* dst = ei + E;
    const int NB = (N + BN - 1) / BN;

    // workspace carve (all 16B aligned)
    char* w = (char*)d_ws;
    unsigned short* Ab  = (unsigned short*)w; w += (size_t)N * DH * 2;
    unsigned short* Bb  = (unsigned short*)w; w += (size_t)N * DH * 2;
    int*      csr    = (int*)w;      w += (size_t)E * 4;
    unsigned* ebuf   = (unsigned*)w; w += (size_t)E * 4;
    unsigned* bcnt   = (unsigned*)w; w += MAXNB * 4;
    unsigned* cursor = (unsigned*)w; w += 16;
    unsigned* bbase  = (unsigned*)w; w += MAXNB * 4;
    unsigned* bpos   = (unsigned*)w; w += MAXNB * 4;
    unsigned* off    = (unsigned*)w; w += (size_t)N * 4;
    unsigned* cnt    = (unsigned*)w; w += (size_t)N * 4;
    float*    nrm    = (float*)w;    w += (size_t)N * 4;
    unsigned short* Wt  = (unsigned short*)w; w += 3 * DH * DH * 2;
    unsigned short* Wft = (unsigned short*)w; w += 48 * DH * 2;
    float*    bfh    = (float*)w;    w += 64 * 4;

    const int gC = (E + CH - 1) / CH;

    hipMemsetAsync(bcnt, 0, MAXNB * 4 + 16, stream);   // bcnt + cursor
    bucket_hist   <<<gC, 256, 0, stream>>>(dst, E, bcnt);
    bucket_alloc  <<<(NB + 255) / 256, 256, 0, stream>>>(bcnt, bbase, bpos, cursor, NB);
    bucket_scatter<<<gC, 256, 0, stream>>>(src, dst, E, bpos, ebuf);
    bucket_csr    <<<NB, 256, 0, stream>>>(ebuf, bbase, bcnt, off, cnt, nrm, csr, N);
    prep_w<<<(3 * DH * DH + 48 * DH + 48 + 255) / 256, 256, 0, stream>>>(
        W1, W2, W3, Wp1, bp1, Wp2, bp2, Wt, Wft, bfh);

    const int gG = (N + 127) / 128;
    const int gF = (N + 63) / 64;

    gemm_mfma_f32<<<gG, 256, 0, stream>>>(x, Wt, nrm, Ab, N);
    agg_gemm<<<gF, 256, 0, stream>>>((const uint4*)Ab, csr, off, cnt, nrm, b1,
                                     Wt + DH * DH, Bb, N);
    agg_gemm<<<gF, 256, 0, stream>>>((const uint4*)Bb, csr, off, cnt, nrm, b2,
                                     Wt + 2 * DH * DH, Ab, N);
    agg_head<<<gF, 256, 0, stream>>>((const uint4*)Ab, csr, off, cnt, nrm, b3,
                                     Wft, bfh, out, N);
}

// Round 10
// 432.603 us; speedup vs baseline: 1.1515x; 1.0497x over previous
//
#include <hip/hip_runtime.h>
#include <hip/hip_bf16.h>
#include <math.h>

// ---------------------------------------------------------------------------
// GCN: 3x GCNConv(128->128) + fused (Wp1@Wp2) head + log_softmax.
// Round 10: R6 fused structure (best: 418 us) + DEGREE-SORTED node permutation.
// R6's only defect was barrier makespan = max(d_i over 16 nodes) ~ 1.34x mean
// (matches 3.59->2.68 TB/s). Counting-sort nodes by degree -> each block's 16
// nodes have equal degree -> max ~= mean. Descending order so long blocks
// dispatch first. Per-node summation order unchanged -> bit-identical output.
// ---------------------------------------------------------------------------

#define DH 128    // feature dim (D == H == 128)
#define NC 40     // classes
#define BN 256    // nodes per bucket
#define MAXNB 512 // max buckets (N <= 131072)
#define CH 8192   // edges per scatter block
#define ECAP 6144 // LDS edge capacity in bucket_csr
#define SP 136    // LDS row stride (elems): 128 + 8 pad

typedef __attribute__((ext_vector_type(8))) short bf16x8;
typedef __attribute__((ext_vector_type(4))) float f32x4;

__device__ __forceinline__ unsigned short f2bf(float f) {
    unsigned u = __float_as_uint(f);
    unsigned r = (u + 0x7fffu + ((u >> 16) & 1u)) >> 16;   // RNE
    return (unsigned short)r;
}
__device__ __forceinline__ unsigned pack2(float lo, float hi) {
    return (unsigned)f2bf(lo) | ((unsigned)f2bf(hi) << 16);
}

// ---------------- bucket-level histogram (LDS, then coalesced merge) --------

__global__ __launch_bounds__(256) void bucket_hist(const int* __restrict__ dst, int E,
                                                   unsigned* __restrict__ bcnt) {
    __shared__ unsigned h[MAXNB];
    int tid = threadIdx.x;
    for (int i = tid; i < MAXNB; i += 256) h[i] = 0;
    __syncthreads();
    int e0 = blockIdx.x * CH;
    int e1 = min(e0 + CH, E);
    for (int i = e0 + tid; i < e1; i += 256)
        atomicAdd(&h[dst[i] >> 8], 1u);
    __syncthreads();
    for (int i = tid; i < MAXNB; i += 256)
        if (h[i]) atomicAdd(&bcnt[i], h[i]);
}

__global__ __launch_bounds__(256) void bucket_alloc(const unsigned* __restrict__ bcnt,
                                                    unsigned* __restrict__ bbase,
                                                    unsigned* __restrict__ bpos,
                                                    unsigned* __restrict__ cursor, int NB) {
    int i = blockIdx.x * 256 + threadIdx.x;
    if (i < NB) {
        unsigned c = bcnt[i];
        unsigned o = atomicAdd(cursor, c);
        bbase[i] = o;
        bpos[i] = o;
    }
}

__global__ __launch_bounds__(256) void bucket_scatter(const int* __restrict__ src,
                                                      const int* __restrict__ dst, int E,
                                                      unsigned* __restrict__ bpos,
                                                      unsigned* __restrict__ ebuf) {
    __shared__ unsigned hist[MAXNB];
    __shared__ unsigned lbase[MAXNB];
    __shared__ unsigned gbase[MAXNB];
    __shared__ unsigned cur[MAXNB];
    __shared__ unsigned sorted[CH];
    __shared__ unsigned short sbkt[CH];
    __shared__ unsigned total;

    int tid = threadIdx.x;
    int e0 = blockIdx.x * CH;
    int nE = min(CH, E - e0);

    for (int i = tid; i < MAXNB; i += 256) { hist[i] = 0; cur[i] = 0; }
    if (tid == 0) total = 0;
    __syncthreads();

    for (int i = tid; i < nE; i += 256)
        atomicAdd(&hist[dst[e0 + i] >> 8], 1u);
    __syncthreads();

    for (int i = tid; i < MAXNB; i += 256) {
        unsigned h = hist[i];
        lbase[i] = h ? atomicAdd(&total, h) : 0u;
        gbase[i] = h ? atomicAdd(&bpos[i], h) : 0u;
    }
    __syncthreads();

    for (int i = tid; i < nE; i += 256) {
        int s = src[e0 + i];
        int d = dst[e0 + i];
        unsigned b = (unsigned)d >> 8;
        unsigned r = atomicAdd(&cur[b], 1u);
        unsigned p = lbase[b] + r;
        sorted[p] = ((unsigned)s << 8) | ((unsigned)d & 255u);
        sbkt[p] = (unsigned short)b;
    }
    __syncthreads();

    for (int p = tid; p < nE; p += 256) {
        unsigned b = sbkt[p];
        ebuf[gbase[b] + (p - lbase[b])] = sorted[p];
    }
}

__global__ __launch_bounds__(256) void bucket_csr(const unsigned* __restrict__ ebuf,
                                                  const unsigned* __restrict__ bbase,
                                                  const unsigned* __restrict__ bcnt,
                                                  unsigned* __restrict__ off,
                                                  unsigned* __restrict__ cnt,
                                                  float* __restrict__ nrm,
                                                  int* __restrict__ csr, int N) {
    __shared__ unsigned h[BN];
    __shared__ unsigned nb[BN];
    __shared__ unsigned ncur[BN];
    __shared__ int lcsr[ECAP];
    __shared__ unsigned tot;

    int b = blockIdx.x;
    int tid = threadIdx.x;
    unsigned ebase = bbase[b];
    unsigned ecnt = bcnt[b];

    h[tid] = 0;
    if (tid == 0) tot = 0;
    __syncthreads();

    for (unsigned i = tid; i < ecnt; i += 256)
        atomicAdd(&h[ebuf[ebase + i] & 255u], 1u);
    __syncthreads();

    unsigned myh = h[tid];
    unsigned mybase = myh ? atomicAdd(&tot, myh) : 0u;
    nb[tid] = mybase;
    ncur[tid] = 0;
    int node = b * BN + tid;
    if (node < N) {
        off[node] = ebase + mybase;
        cnt[node] = myh;
        nrm[node] = rsqrtf((float)myh + 1.0f);
    }
    __syncthreads();

    if (ecnt <= ECAP) {
        for (unsigned i = tid; i < ecnt; i += 256) {
            unsigned v = ebuf[ebase + i];
            unsigned nl = v & 255u;
            unsigned r = atomicAdd(&ncur[nl], 1u);
            lcsr[nb[nl] + r] = (int)(v >> 8);
        }
        __syncthreads();
        for (unsigned i = tid; i < ecnt; i += 256)
            csr[ebase + i] = lcsr[i];
    } else {
        for (unsigned i = tid; i < ecnt; i += 256) {
            unsigned v = ebuf[ebase + i];
            unsigned nl = v & 255u;
            unsigned r = atomicAdd(&ncur[nl], 1u);
            csr[ebase + nb[nl] + r] = (int)(v >> 8);
        }
    }
}

// ---------------- degree counting sort: perm = nodes by descending degree ---

__global__ __launch_bounds__(256) void deg_hist(const unsigned* __restrict__ cnt, int N,
                                                unsigned* __restrict__ dh) {
    __shared__ unsigned h[256];
    int t = threadIdx.x;
    h[t] = 0;
    __syncthreads();
    int i = blockIdx.x * 256 + t;
    if (i < N) atomicAdd(&h[min(cnt[i], 255u)], 1u);
    __syncthreads();
    if (h[t]) atomicAdd(&dh[t], h[t]);
}

// binpos[d] = number of nodes with degree > d  (descending order base)
__global__ __launch_bounds__(256) void deg_scan(const unsigned* __restrict__ dh,
                                                unsigned* __restrict__ binpos) {
    __shared__ unsigned s[256];
    int t = threadIdx.x;
    s[t] = dh[t];
    __syncthreads();
    unsigned sum = 0;
    for (int d = t + 1; d < 256; ++d) sum += s[d];
    binpos[t] = sum;
}

__global__ __launch_bounds__(256) void deg_scatter(const unsigned* __restrict__ cnt, int N,
                                                   unsigned* __restrict__ binpos,
                                                   int* __restrict__ perm) {
    __shared__ unsigned h[256], base[256], cur[256];
    int t = threadIdx.x;
    h[t] = 0; cur[t] = 0;
    __syncthreads();
    int i = blockIdx.x * 256 + t;
    unsigned d = 0;
    if (i < N) { d = min(cnt[i], 255u); atomicAdd(&h[d], 1u); }
    __syncthreads();
    if (h[t]) base[t] = atomicAdd(&binpos[t], h[t]);
    __syncthreads();
    if (i < N) {
        unsigned r = atomicAdd(&cur[d], 1u);
        perm[base[d] + r] = i;
    }
}

// ---------------- weight prep: Wt (3 layers, transposed bf16) + fused head --

__global__ __launch_bounds__(256) void prep_w(const float* __restrict__ W1,
                                              const float* __restrict__ W2,
                                              const float* __restrict__ W3,
                                              const float* __restrict__ Wp1,
                                              const float* __restrict__ bp1,
                                              const float* __restrict__ Wp2,
                                              const float* __restrict__ bp2,
                                              unsigned short* __restrict__ Wt,
                                              unsigned short* __restrict__ Wft,
                                              float* __restrict__ bfh) {
    int id = blockIdx.x * 256 + threadIdx.x;
    if (id < 3 * DH * DH) {
        int l = id >> 14, r = id & (DH * DH - 1);
        int k = r >> 7, n = r & 127;
        const float* W = (l == 0) ? W1 : (l == 1) ? W2 : W3;
        Wt[l * DH * DH + n * DH + k] = f2bf(W[k * DH + n]);
    } else if (id < 3 * DH * DH + 48 * DH) {
        int o = id - 3 * DH * DH;
        int c = o >> 7, k = o & 127;
        float acc = 0.f;
        if (c < NC)
            for (int j = 0; j < DH; ++j) acc += Wp1[k * DH + j] * Wp2[j * NC + c];
        Wft[c * DH + k] = f2bf(acc);
    } else if (id < 3 * DH * DH + 48 * DH + 48) {
        int c = id - 3 * DH * DH - 48 * DH;
        float acc = 0.f;
        if (c < NC) {
            acc = bp2[c];
            for (int j = 0; j < DH; ++j) acc += bp1[j] * Wp2[j * NC + c];
        }
        bfh[c] = acc;
    }
}

// ---------------- layer-1 MFMA GEMM: Ab = bf16(nrm * (x_f32 @ W1)) ----------

__global__ __launch_bounds__(256) void gemm_mfma_f32(const float* __restrict__ X,
                                                     const unsigned short* __restrict__ Wt,
                                                     const float* __restrict__ nrm,
                                                     unsigned short* __restrict__ outb,
                                                     int nrows) {
    const int tid = threadIdx.x;
    const int wave = tid >> 6;
    const int lane = tid & 63;
    const int m = lane & 15;
    const int quad = lane >> 4;
    const int rbase = blockIdx.x * 128 + wave * 32;

    union U8 { bf16x8 v; unsigned u[4]; };

    f32x4 acc[2][8];
#pragma unroll
    for (int rt = 0; rt < 2; ++rt)
#pragma unroll
        for (int ct = 0; ct < 8; ++ct) acc[rt][ct] = (f32x4){0.f, 0.f, 0.f, 0.f};

#pragma unroll
    for (int kt = 0; kt < 4; ++kt) {
        const int kof = kt * 32 + quad * 8;
        bf16x8 a[2], b[8];
#pragma unroll
        for (int rt = 0; rt < 2; ++rt) {
            int r = rbase + rt * 16 + m;
            r = (r < nrows) ? r : (nrows - 1);
            const float* p = X + (size_t)r * DH + kof;
            float4 u0 = *(const float4*)p;
            float4 u1 = *(const float4*)(p + 4);
            U8 t;
            t.u[0] = pack2(u0.x, u0.y);
            t.u[1] = pack2(u0.z, u0.w);
            t.u[2] = pack2(u1.x, u1.y);
            t.u[3] = pack2(u1.z, u1.w);
            a[rt] = t.v;
        }
#pragma unroll
        for (int ct = 0; ct < 8; ++ct)
            b[ct] = *(const bf16x8*)(Wt + (ct * 16 + m) * DH + kof);
#pragma unroll
        for (int rt = 0; rt < 2; ++rt)
#pragma unroll
            for (int ct = 0; ct < 8; ++ct)
                acc[rt][ct] = __builtin_amdgcn_mfma_f32_16x16x32_bf16(a[rt], b[ct], acc[rt][ct], 0, 0, 0);
    }

#pragma unroll
    for (int rt = 0; rt < 2; ++rt)
#pragma unroll
        for (int reg = 0; reg < 4; ++reg) {
            int r = rbase + rt * 16 + quad * 4 + reg;
            if (r < nrows) {
                float s = nrm[r];
#pragma unroll
                for (int ct = 0; ct < 8; ++ct)
                    outb[(size_t)r * DH + ct * 16 + m] = f2bf(acc[rt][ct][reg] * s);
            }
        }
}

// ---------------- gather phase (16 perm-nodes/block, degree-homogeneous) ----
// group g handles node perm[blk*16+g]; 16 lanes x uint4, 4-deep unroll
// (64 B/lane in flight -> R4's 3.59 TB/s load shape). Equal degrees within a
// block -> barrier costs ~nothing. z -> bf16 into sA[g].

__device__ __forceinline__ void bf8_add(float* acc, uint4 v) {
    acc[0] += __uint_as_float(v.x << 16);
    acc[1] += __uint_as_float(v.x & 0xffff0000u);
    acc[2] += __uint_as_float(v.y << 16);
    acc[3] += __uint_as_float(v.y & 0xffff0000u);
    acc[4] += __uint_as_float(v.z << 16);
    acc[5] += __uint_as_float(v.z & 0xffff0000u);
    acc[6] += __uint_as_float(v.w << 16);
    acc[7] += __uint_as_float(v.w & 0xffff0000u);
}

__device__ __forceinline__ void gather_phase(const uint4* __restrict__ Abf,
                                             const int* __restrict__ csr,
                                             const unsigned* __restrict__ off,
                                             const unsigned* __restrict__ cnt,
                                             const float* __restrict__ nrm,
                                             const float* __restrict__ bias,
                                             const int* __restrict__ perm,
                                             unsigned short (*sA)[SP], int N) {
    const int tid = threadIdx.x;
    const int g = tid >> 4;
    const int lane = tid & 15;
    const int idx = blockIdx.x * 16 + g;
    if (idx < N) {
        const int node = perm[idx];
        float acc[8];
        {
            uint4 v = Abf[(size_t)node * 16 + lane];   // self term
            acc[0] = __uint_as_float(v.x << 16);
            acc[1] = __uint_as_float(v.x & 0xffff0000u);
            acc[2] = __uint_as_float(v.y << 16);
            acc[3] = __uint_as_float(v.y & 0xffff0000u);
            acc[4] = __uint_as_float(v.z << 16);
            acc[5] = __uint_as_float(v.z & 0xffff0000u);
            acc[6] = __uint_as_float(v.w << 16);
            acc[7] = __uint_as_float(v.w & 0xffff0000u);
        }
        unsigned o = off[node];
        unsigned d = cnt[node];

        unsigned e = 0;
        for (; e + 4 <= d; e += 4) {
            int s0 = csr[o + e + 0];
            int s1 = csr[o + e + 1];
            int s2 = csr[o + e + 2];
            int s3 = csr[o + e + 3];
            uint4 v0 = Abf[(size_t)s0 * 16 + lane];
            uint4 v1 = Abf[(size_t)s1 * 16 + lane];
            uint4 v2 = Abf[(size_t)s2 * 16 + lane];
            uint4 v3 = Abf[(size_t)s3 * 16 + lane];
            bf8_add(acc, v0);
            bf8_add(acc, v1);
            bf8_add(acc, v2);
            bf8_add(acc, v3);
        }
        for (; e < d; ++e) {
            int s = csr[o + e];
            uint4 v = Abf[(size_t)s * 16 + lane];
            bf8_add(acc, v);
        }

        float nm = nrm[node];
        float4 b0 = *(const float4*)(bias + lane * 8);
        float4 b1 = *(const float4*)(bias + lane * 8 + 4);
        unsigned short* p = &sA[g][lane * 8];
        p[0] = f2bf(fmaxf(acc[0] * nm + b0.x, 0.f));
        p[1] = f2bf(fmaxf(acc[1] * nm + b0.y, 0.f));
        p[2] = f2bf(fmaxf(acc[2] * nm + b0.z, 0.f));
        p[3] = f2bf(fmaxf(acc[3] * nm + b0.w, 0.f));
        p[4] = f2bf(fmaxf(acc[4] * nm + b1.x, 0.f));
        p[5] = f2bf(fmaxf(acc[5] * nm + b1.y, 0.f));
        p[6] = f2bf(fmaxf(acc[6] * nm + b1.z, 0.f));
        p[7] = f2bf(fmaxf(acc[7] * nm + b1.w, 0.f));
    }
    __syncthreads();
}

// ---------------- fused: aggregate + next-layer GEMM ------------------------
// Phase 2: 4 waves x 2 col-tiles of 16x16x32 MFMA; store rows to perm[idx].

__global__ __launch_bounds__(256) void agg_gemm(const uint4* __restrict__ Abf,
                                                const int* __restrict__ csr,
                                                const unsigned* __restrict__ off,
                                                const unsigned* __restrict__ cnt,
                                                const float* __restrict__ nrm,
                                                const float* __restrict__ bias,
                                                const int* __restrict__ perm,
                                                const unsigned short* __restrict__ Wt,
                                                unsigned short* __restrict__ outb, int N) {
    __shared__ unsigned short sA[16][SP];
    gather_phase(Abf, csr, off, cnt, nrm, bias, perm, sA, N);

    const int tid = threadIdx.x;
    const int wave = tid >> 6;
    const int l64 = tid & 63;
    const int m = l64 & 15;
    const int quad = l64 >> 4;

    f32x4 acc[2];
    acc[0] = (f32x4){0.f, 0.f, 0.f, 0.f};
    acc[1] = (f32x4){0.f, 0.f, 0.f, 0.f};

#pragma unroll
    for (int kt = 0; kt < 4; ++kt) {
        const int kof = kt * 32 + quad * 8;
        bf16x8 a = *(const bf16x8*)&sA[m][kof];
#pragma unroll
        for (int c2 = 0; c2 < 2; ++c2) {
            const int ct = wave * 2 + c2;
            bf16x8 b = *(const bf16x8*)(Wt + (ct * 16 + m) * DH + kof);
            acc[c2] = __builtin_amdgcn_mfma_f32_16x16x32_bf16(a, b, acc[c2], 0, 0, 0);
        }
    }

#pragma unroll
    for (int reg = 0; reg < 4; ++reg) {
        int idx = blockIdx.x * 16 + quad * 4 + reg;
        if (idx < N) {
            int r = perm[idx];
            float s = nrm[r];
#pragma unroll
            for (int c2 = 0; c2 < 2; ++c2)
                outb[(size_t)r * DH + (wave * 2 + c2) * 16 + m] = f2bf(acc[c2][reg] * s);
        }
    }
}

// ---------------- fused: aggregate + head GEMM + log_softmax ----------------

__global__ __launch_bounds__(256) void agg_head(const uint4* __restrict__ Abf,
                                                const int* __restrict__ csr,
                                                const unsigned* __restrict__ off,
                                                const unsigned* __restrict__ cnt,
                                                const float* __restrict__ nrm,
                                                const float* __restrict__ bias,
                                                const int* __restrict__ perm,
                                                const unsigned short* __restrict__ Wft,
                                                const float* __restrict__ bfh,
                                                float* __restrict__ out, int N) {
    __shared__ unsigned short sA[16][SP];
    gather_phase(Abf, csr, off, cnt, nrm, bias, perm, sA, N);

    const int tid = threadIdx.x;
    if (tid >= 64) return;                 // one wave does the 16x48 head
    const int m = tid & 15;
    const int quad = tid >> 4;

    f32x4 acc[3];
#pragma unroll
    for (int ct = 0; ct < 3; ++ct) acc[ct] = (f32x4){0.f, 0.f, 0.f, 0.f};

#pragma unroll
    for (int kt = 0; kt < 4; ++kt) {
        const int kof = kt * 32 + quad * 8;
        bf16x8 a = *(const bf16x8*)&sA[m][kof];
#pragma unroll
        for (int ct = 0; ct < 3; ++ct) {
            bf16x8 b = *(const bf16x8*)(Wft + (ct * 16 + m) * DH + kof);
            acc[ct] = __builtin_amdgcn_mfma_f32_16x16x32_bf16(a, b, acc[ct], 0, 0, 0);
        }
    }

    float bias0 = bfh[m];
    float bias1 = bfh[16 + m];
    float bias2 = bfh[32 + m];

#pragma unroll
    for (int reg = 0; reg < 4; ++reg) {
        float v0 = acc[0][reg] + bias0;
        float v1 = acc[1][reg] + bias1;
        float v2 = (m < 8) ? (acc[2][reg] + bias2) : -1e30f;
        float mx = fmaxf(fmaxf(v0, v1), v2);
#pragma unroll
        for (int dlt = 1; dlt < 16; dlt <<= 1) mx = fmaxf(mx, __shfl_xor(mx, dlt));
        float s = __expf(v0 - mx) + __expf(v1 - mx) + ((m < 8) ? __expf(v2 - mx) : 0.f);
#pragma unroll
        for (int dlt = 1; dlt < 16; dlt <<= 1) s += __shfl_xor(s, dlt);
        float ls = mx + __logf(s);
        int idx = blockIdx.x * 16 + quad * 4 + reg;
        if (idx < N) {
            int r = perm[idx];
            out[(size_t)r * NC + m] = v0 - ls;
            out[(size_t)r * NC + 16 + m] = v1 - ls;
            if (m < 8) out[(size_t)r * NC + 32 + m] = v2 - ls;
        }
    }
}

// ---------------------------------------------------------------------------

extern "C" void kernel_launch(void* const* d_in, const int* in_sizes, int n_in,
                              void* d_out, int out_size, void* d_ws, size_t ws_size,
                              hipStream_t stream) {
    const float* x   = (const float*)d_in[0];
    const int*   ei  = (const int*)d_in[1];
    const float* W1  = (const float*)d_in[2];
    const float* b1  = (const float*)d_in[3];
    const float* W2  = (const float*)d_in[4];
    const float* b2  = (const float*)d_in[5];
    const float* W3  = (const float*)d_in[6];
    const float* b3  = (const float*)d_in[7];
    const float* Wp1 = (const float*)d_in[8];
    const float* bp1 = (const float*)d_in[9];
    const float* Wp2 = (const float*)d_in[10];
    const float* bp2 = (const float*)d_in[11];
    float* out = (float*)d_out;

    const int N = in_sizes[0] / DH;
    const int E = in_sizes[1] / 2;
    const int* src = ei;
    const int* dst = ei + E;
    const int NB = (N + BN - 1) / BN;

    // workspace carve (all 16B aligned)
    char* w = (char*)d_ws;
    unsigned short* Ab  = (unsigned short*)w; w += (size_t)N * DH * 2;
    unsigned short* Bb  = (unsigned short*)w; w += (size_t)N * DH * 2;
    int*      csr    = (int*)w;      w += (size_t)E * 4;
    unsigned* ebuf   = (unsigned*)w; w += (size_t)E * 4;
    unsigned* bcnt   = (unsigned*)w; w += MAXNB * 4;
    unsigned* cursor = (unsigned*)w; w += 16;
    unsigned* dh     = (unsigned*)w; w += 256 * 4;       // zeroed with bcnt
    unsigned* bbase  = (unsigned*)w; w += MAXNB * 4;
    unsigned* bpos   = (unsigned*)w; w += MAXNB * 4;
    unsigned* binpos = (unsigned*)w; w += 256 * 4;
    unsigned* off    = (unsigned*)w; w += (size_t)N * 4;
    unsigned* cnt    = (unsigned*)w; w += (size_t)N * 4;
    float*    nrm    = (float*)w;    w += (size_t)N * 4;
    int*      perm   = (int*)w;      w += (size_t)((N + 31) & ~31) * 4;
    unsigned short* Wt  = (unsigned short*)w; w += 3 * DH * DH * 2;
    unsigned short* Wft = (unsigned short*)w; w += 48 * DH * 2;
    float*    bfh    = (float*)w;    w += 64 * 4;

    const int gC = (E + CH - 1) / CH;
    const int gN = (N + 255) / 256;

    hipMemsetAsync(bcnt, 0, MAXNB * 4 + 16 + 256 * 4, stream);   // bcnt+cursor+dh
    bucket_hist   <<<gC, 256, 0, stream>>>(dst, E, bcnt);
    bucket_alloc  <<<(NB + 255) / 256, 256, 0, stream>>>(bcnt, bbase, bpos, cursor, NB);
    bucket_scatter<<<gC, 256, 0, stream>>>(src, dst, E, bpos, ebuf);
    bucket_csr    <<<NB, 256, 0, stream>>>(ebuf, bbase, bcnt, off, cnt, nrm, csr, N);
    deg_hist      <<<gN, 256, 0, stream>>>(cnt, N, dh);
    deg_scan      <<<1, 256, 0, stream>>>(dh, binpos);
    deg_scatter   <<<gN, 256, 0, stream>>>(cnt, N, binpos, perm);
    prep_w<<<(3 * DH * DH + 48 * DH + 48 + 255) / 256, 256, 0, stream>>>(
        W1, W2, W3, Wp1, bp1, Wp2, bp2, Wt, Wft, bfh);

    const int gG = (N + 127) / 128;
    const int gF = (N + 15) / 16;

    gemm_mfma_f32<<<gG, 256, 0, stream>>>(x, Wt, nrm, Ab, N);
    agg_gemm<<<gF, 256, 0, stream>>>((const uint4*)Ab, csr, off, cnt, nrm, b1, perm,
                                     Wt + DH * DH, Bb, N);
    agg_gemm<<<gF, 256, 0, stream>>>((const uint4*)Bb, csr, off, cnt, nrm, b2, perm,
                                     Wt + 2 * DH * DH, Ab, N);
    agg_head<<<gF, 256, 0, stream>>>((const uint4*)Ab, csr, off, cnt, nrm, b3, perm,
                                     Wft, bfh, out, N);
}

// Round 11
// 415.596 us; speedup vs baseline: 1.1986x; 1.0409x over previous
//
#include <hip/hip_runtime.h>
#include <hip/hip_bf16.h>
#include <math.h>

// ---------------------------------------------------------------------------
// GCN: 3x GCNConv(128->128) + fused (Wp1@Wp2) head + log_softmax.
// Round 11: perm-ordered CSR. R10's degree sort fixed barrier makespan but
// scattered the csr segments (+16 MB FETCH/layer). Now the counting-sort
// structure gives a CLOSED-FORM edge offset per perm position
// (off2 = estart[d] + rank*d), so csr is laid out in perm order:
//  - gather reads ONE coalesced uint/node (pd2 = off2<<9|d; nrm = rsqrt(d+1))
//  - each block's csr segment is one contiguous run
//  - node id + nrm stashed in LDS for the MFMA epilogue
// deg_hist folded into bucket_deg; gather LDS write vectorized to uint4.
// ---------------------------------------------------------------------------

#define DH 128    // feature dim (D == H == 128)
#define NC 40     // classes
#define BN 256    // nodes per bucket
#define MAXNB 512 // max buckets (N <= 131072)
#define CH 8192   // edges per scatter block
#define ECAP 6144 // LDS edge capacity in bucket_fill (mean ~4096, +30 sigma)
#define SP 136    // LDS row stride (elems): 128 + 8 pad

typedef __attribute__((ext_vector_type(8))) short bf16x8;
typedef __attribute__((ext_vector_type(4))) float f32x4;

__device__ __forceinline__ unsigned short f2bf(float f) {
    unsigned u = __float_as_uint(f);
    unsigned r = (u + 0x7fffu + ((u >> 16) & 1u)) >> 16;   // RNE
    return (unsigned short)r;
}
__device__ __forceinline__ unsigned pack2(float lo, float hi) {
    return (unsigned)f2bf(lo) | ((unsigned)f2bf(hi) << 16);
}

// ---------------- bucket-level histogram (LDS, then coalesced merge) --------

__global__ __launch_bounds__(256) void bucket_hist(const int* __restrict__ dst, int E,
                                                   unsigned* __restrict__ bcnt) {
    __shared__ unsigned h[MAXNB];
    int tid = threadIdx.x;
    for (int i = tid; i < MAXNB; i += 256) h[i] = 0;
    __syncthreads();
    int e0 = blockIdx.x * CH;
    int e1 = min(e0 + CH, E);
    for (int i = e0 + tid; i < e1; i += 256)
        atomicAdd(&h[dst[i] >> 8], 1u);
    __syncthreads();
    for (int i = tid; i < MAXNB; i += 256)
        if (h[i]) atomicAdd(&bcnt[i], h[i]);
}

__global__ __launch_bounds__(256) void bucket_alloc(const unsigned* __restrict__ bcnt,
                                                    unsigned* __restrict__ bbase,
                                                    unsigned* __restrict__ bpos,
                                                    unsigned* __restrict__ cursor, int NB) {
    int i = blockIdx.x * 256 + threadIdx.x;
    if (i < NB) {
        unsigned c = bcnt[i];
        unsigned o = atomicAdd(cursor, c);
        bbase[i] = o;
        bpos[i] = o;
    }
}

__global__ __launch_bounds__(256) void bucket_scatter(const int* __restrict__ src,
                                                      const int* __restrict__ dst, int E,
                                                      unsigned* __restrict__ bpos,
                                                      unsigned* __restrict__ ebuf) {
    __shared__ unsigned hist[MAXNB];
    __shared__ unsigned lbase[MAXNB];
    __shared__ unsigned gbase[MAXNB];
    __shared__ unsigned cur[MAXNB];
    __shared__ unsigned sorted[CH];
    __shared__ unsigned short sbkt[CH];
    __shared__ unsigned total;

    int tid = threadIdx.x;
    int e0 = blockIdx.x * CH;
    int nE = min(CH, E - e0);

    for (int i = tid; i < MAXNB; i += 256) { hist[i] = 0; cur[i] = 0; }
    if (tid == 0) total = 0;
    __syncthreads();

    for (int i = tid; i < nE; i += 256)
        atomicAdd(&hist[dst[e0 + i] >> 8], 1u);
    __syncthreads();

    for (int i = tid; i < MAXNB; i += 256) {
        unsigned h = hist[i];
        lbase[i] = h ? atomicAdd(&total, h) : 0u;
        gbase[i] = h ? atomicAdd(&bpos[i], h) : 0u;
    }
    __syncthreads();

    for (int i = tid; i < nE; i += 256) {
        int s = src[e0 + i];
        int d = dst[e0 + i];
        unsigned b = (unsigned)d >> 8;
        unsigned r = atomicAdd(&cur[b], 1u);
        unsigned p = lbase[b] + r;
        sorted[p] = ((unsigned)s << 8) | ((unsigned)d & 255u);
        sbkt[p] = (unsigned short)b;
    }
    __syncthreads();

    for (int p = tid; p < nE; p += 256) {
        unsigned b = sbkt[p];
        ebuf[gbase[b] + (p - lbase[b])] = sorted[p];
    }
}

// ---------------- per-bucket degree + nrm + degree histogram ---------------

__global__ __launch_bounds__(256) void bucket_deg(const unsigned* __restrict__ ebuf,
                                                  const unsigned* __restrict__ bbase,
                                                  const unsigned* __restrict__ bcnt,
                                                  unsigned* __restrict__ cnt,
                                                  float* __restrict__ nrm,
                                                  unsigned* __restrict__ dh, int N) {
    __shared__ unsigned h[BN];
    __shared__ unsigned dhh[256];
    int b = blockIdx.x, tid = threadIdx.x;
    unsigned ebase = bbase[b], ecnt = bcnt[b];
    h[tid] = 0; dhh[tid] = 0;
    __syncthreads();
    for (unsigned i = tid; i < ecnt; i += 256)
        atomicAdd(&h[ebuf[ebase + i] & 255u], 1u);
    __syncthreads();
    int node = b * BN + tid;
    unsigned myh = h[tid];
    if (node < N) {
        cnt[node] = myh;
        nrm[node] = rsqrtf((float)myh + 1.0f);
        atomicAdd(&dhh[min(myh, 255u)], 1u);
    }
    __syncthreads();
    if (dhh[tid]) atomicAdd(&dh[tid], dhh[tid]);
}

// nstart[d] = #nodes with degree > d; estart[d] = #edges of nodes with deg > d
__global__ __launch_bounds__(256) void deg_scan(const unsigned* __restrict__ dh,
                                                unsigned* __restrict__ binpos,
                                                unsigned* __restrict__ nstart0,
                                                unsigned* __restrict__ estart) {
    __shared__ unsigned s[256];
    int t = threadIdx.x;
    s[t] = dh[t];
    __syncthreads();
    unsigned ns = 0, es = 0;
    for (int d = t + 1; d < 256; ++d) { ns += s[d]; es += s[d] * (unsigned)d; }
    binpos[t] = ns;
    nstart0[t] = ns;
    estart[t] = es;
}

__global__ __launch_bounds__(256) void deg_scatter(const unsigned* __restrict__ cnt, int N,
                                                   unsigned* __restrict__ binpos,
                                                   const unsigned* __restrict__ nstart0,
                                                   const unsigned* __restrict__ estart,
                                                   int* __restrict__ perm,
                                                   unsigned* __restrict__ pd2,
                                                   unsigned* __restrict__ offN) {
    __shared__ unsigned h[256], base[256], cur[256], sns[256], ses[256];
    int t = threadIdx.x;
    h[t] = 0; cur[t] = 0; sns[t] = nstart0[t]; ses[t] = estart[t];
    __syncthreads();
    int i = blockIdx.x * 256 + t;
    unsigned d = 0;
    if (i < N) { d = min(cnt[i], 255u); atomicAdd(&h[d], 1u); }
    __syncthreads();
    if (h[t]) base[t] = atomicAdd(&binpos[t], h[t]);
    __syncthreads();
    if (i < N) {
        unsigned r = atomicAdd(&cur[d], 1u);
        unsigned idx = base[d] + r;
        unsigned off2 = ses[d] + (idx - sns[d]) * d;
        perm[idx] = i;
        pd2[idx] = (off2 << 9) | d;     // d < 512 (Poisson(16) max ~50)
        offN[i] = off2;
    }
}

// ---------------- csr fill in perm order (LDS grouped, coalesced out) -------

__global__ __launch_bounds__(256) void bucket_fill(const unsigned* __restrict__ ebuf,
                                                   const unsigned* __restrict__ bbase,
                                                   const unsigned* __restrict__ bcnt,
                                                   const unsigned* __restrict__ offN,
                                                   int* __restrict__ csr, int N) {
    __shared__ unsigned h[BN], lb[BN], cur[BN], ofs[BN];
    __shared__ int lcsr[ECAP];
    __shared__ unsigned char snl[ECAP];
    __shared__ unsigned tot;

    int b = blockIdx.x, tid = threadIdx.x;
    unsigned ebase = bbase[b], ecnt = bcnt[b];
    int node = b * BN + tid;
    h[tid] = 0; cur[tid] = 0;
    ofs[tid] = (node < N) ? offN[node] : 0u;
    if (tid == 0) tot = 0;
    __syncthreads();

    for (unsigned i = tid; i < ecnt; i += 256)
        atomicAdd(&h[ebuf[ebase + i] & 255u], 1u);
    __syncthreads();

    unsigned myh = h[tid];
    lb[tid] = myh ? atomicAdd(&tot, myh) : 0u;
    __syncthreads();

    if (ecnt <= ECAP) {
        for (unsigned i = tid; i < ecnt; i += 256) {
            unsigned v = ebuf[ebase + i];
            unsigned nl = v & 255u;
            unsigned r = atomicAdd(&cur[nl], 1u);
            unsigned p = lb[nl] + r;
            lcsr[p] = (int)(v >> 8);
            snl[p] = (unsigned char)nl;
        }
        __syncthreads();
        for (unsigned i = tid; i < ecnt; i += 256) {
            unsigned nl = snl[i];
            csr[ofs[nl] + (i - lb[nl])] = lcsr[i];
        }
    } else {
        // statistically unreachable fallback
        for (unsigned i = tid; i < ecnt; i += 256) {
            unsigned v = ebuf[ebase + i];
            unsigned nl = v & 255u;
            unsigned r = atomicAdd(&cur[nl], 1u);
            csr[ofs[nl] + r] = (int)(v >> 8);
        }
    }
}

// ---------------- weight prep: Wt (3 layers, transposed bf16) + fused head --

__global__ __launch_bounds__(256) void prep_w(const float* __restrict__ W1,
                                              const float* __restrict__ W2,
                                              const float* __restrict__ W3,
                                              const float* __restrict__ Wp1,
                                              const float* __restrict__ bp1,
                                              const float* __restrict__ Wp2,
                                              const float* __restrict__ bp2,
                                              unsigned short* __restrict__ Wt,
                                              unsigned short* __restrict__ Wft,
                                              float* __restrict__ bfh) {
    int id = blockIdx.x * 256 + threadIdx.x;
    if (id < 3 * DH * DH) {
        int l = id >> 14, r = id & (DH * DH - 1);
        int k = r >> 7, n = r & 127;
        const float* W = (l == 0) ? W1 : (l == 1) ? W2 : W3;
        Wt[l * DH * DH + n * DH + k] = f2bf(W[k * DH + n]);
    } else if (id < 3 * DH * DH + 48 * DH) {
        int o = id - 3 * DH * DH;
        int c = o >> 7, k = o & 127;
        float acc = 0.f;
        if (c < NC)
            for (int j = 0; j < DH; ++j) acc += Wp1[k * DH + j] * Wp2[j * NC + c];
        Wft[c * DH + k] = f2bf(acc);
    } else if (id < 3 * DH * DH + 48 * DH + 48) {
        int c = id - 3 * DH * DH - 48 * DH;
        float acc = 0.f;
        if (c < NC) {
            acc = bp2[c];
            for (int j = 0; j < DH; ++j) acc += bp1[j] * Wp2[j * NC + c];
        }
        bfh[c] = acc;
    }
}

// ---------------- layer-1 MFMA GEMM: Ab = bf16(nrm * (x_f32 @ W1)) ----------

__global__ __launch_bounds__(256) void gemm_mfma_f32(const float* __restrict__ X,
                                                     const unsigned short* __restrict__ Wt,
                                                     const float* __restrict__ nrm,
                                                     unsigned short* __restrict__ outb,
                                                     int nrows) {
    const int tid = threadIdx.x;
    const int wave = tid >> 6;
    const int lane = tid & 63;
    const int m = lane & 15;
    const int quad = lane >> 4;
    const int rbase = blockIdx.x * 128 + wave * 32;

    union U8 { bf16x8 v; unsigned u[4]; };

    f32x4 acc[2][8];
#pragma unroll
    for (int rt = 0; rt < 2; ++rt)
#pragma unroll
        for (int ct = 0; ct < 8; ++ct) acc[rt][ct] = (f32x4){0.f, 0.f, 0.f, 0.f};

#pragma unroll
    for (int kt = 0; kt < 4; ++kt) {
        const int kof = kt * 32 + quad * 8;
        bf16x8 a[2], b[8];
#pragma unroll
        for (int rt = 0; rt < 2; ++rt) {
            int r = rbase + rt * 16 + m;
            r = (r < nrows) ? r : (nrows - 1);
            const float* p = X + (size_t)r * DH + kof;
            float4 u0 = *(const float4*)p;
            float4 u1 = *(const float4*)(p + 4);
            U8 t;
            t.u[0] = pack2(u0.x, u0.y);
            t.u[1] = pack2(u0.z, u0.w);
            t.u[2] = pack2(u1.x, u1.y);
            t.u[3] = pack2(u1.z, u1.w);
            a[rt] = t.v;
        }
#pragma unroll
        for (int ct = 0; ct < 8; ++ct)
            b[ct] = *(const bf16x8*)(Wt + (ct * 16 + m) * DH + kof);
#pragma unroll
        for (int rt = 0; rt < 2; ++rt)
#pragma unroll
            for (int ct = 0; ct < 8; ++ct)
                acc[rt][ct] = __builtin_amdgcn_mfma_f32_16x16x32_bf16(a[rt], b[ct], acc[rt][ct], 0, 0, 0);
    }

#pragma unroll
    for (int rt = 0; rt < 2; ++rt)
#pragma unroll
        for (int reg = 0; reg < 4; ++reg) {
            int r = rbase + rt * 16 + quad * 4 + reg;
            if (r < nrows) {
                float s = nrm[r];
#pragma unroll
                for (int ct = 0; ct < 8; ++ct)
                    outb[(size_t)r * DH + ct * 16 + m] = f2bf(acc[rt][ct][reg] * s);
            }
        }
}

// ---------------- gather phase (perm order, contiguous csr) -----------------
// group g = perm position blk*16+g; ONE uint pd2 gives edge base + degree;
// nrm recomputed (bit-identical rsqrtf). 16 lanes x uint4, 4-deep unroll.
// Stashes node id + nrm in LDS for the epilogue. Degrees equal within block.

__device__ __forceinline__ void bf8_add(float* acc, uint4 v) {
    acc[0] += __uint_as_float(v.x << 16);
    acc[1] += __uint_as_float(v.x & 0xffff0000u);
    acc[2] += __uint_as_float(v.y << 16);
    acc[3] += __uint_as_float(v.y & 0xffff0000u);
    acc[4] += __uint_as_float(v.z << 16);
    acc[5] += __uint_as_float(v.z & 0xffff0000u);
    acc[6] += __uint_as_float(v.w << 16);
    acc[7] += __uint_as_float(v.w & 0xffff0000u);
}

__device__ __forceinline__ void gather_phase(const uint4* __restrict__ Abf,
                                             const int* __restrict__ csr,
                                             const unsigned* __restrict__ pd2,
                                             const int* __restrict__ perm,
                                             const float* __restrict__ bias,
                                             unsigned short (*sA)[SP],
                                             int* snode, float* snrm, int N) {
    const int tid = threadIdx.x;
    const int g = tid >> 4;
    const int lane = tid & 15;
    const int idx = blockIdx.x * 16 + g;
    if (idx < N) {
        const unsigned pd = pd2[idx];
        const unsigned o = pd >> 9;
        const unsigned d = pd & 511u;
        const int node = perm[idx];

        float acc[8];
        {
            uint4 v = Abf[(size_t)node * 16 + lane];   // self term
            acc[0] = __uint_as_float(v.x << 16);
            acc[1] = __uint_as_float(v.x & 0xffff0000u);
            acc[2] = __uint_as_float(v.y << 16);
            acc[3] = __uint_as_float(v.y & 0xffff0000u);
            acc[4] = __uint_as_float(v.z << 16);
            acc[5] = __uint_as_float(v.z & 0xffff0000u);
            acc[6] = __uint_as_float(v.w << 16);
            acc[7] = __uint_as_float(v.w & 0xffff0000u);
        }

        unsigned e = 0;
        for (; e + 4 <= d; e += 4) {
            int s0 = csr[o + e + 0];
            int s1 = csr[o + e + 1];
            int s2 = csr[o + e + 2];
            int s3 = csr[o + e + 3];
            uint4 v0 = Abf[(size_t)s0 * 16 + lane];
            uint4 v1 = Abf[(size_t)s1 * 16 + lane];
            uint4 v2 = Abf[(size_t)s2 * 16 + lane];
            uint4 v3 = Abf[(size_t)s3 * 16 + lane];
            bf8_add(acc, v0);
            bf8_add(acc, v1);
            bf8_add(acc, v2);
            bf8_add(acc, v3);
        }
        for (; e < d; ++e) {
            int s = csr[o + e];
            uint4 v = Abf[(size_t)s * 16 + lane];
            bf8_add(acc, v);
        }

        float nm = rsqrtf((float)d + 1.0f);
        if (lane == 0) { snode[g] = node; snrm[g] = nm; }
        float4 b0 = *(const float4*)(bias + lane * 8);
        float4 b1 = *(const float4*)(bias + lane * 8 + 4);
        uint4 ov;
        ov.x = pack2(fmaxf(acc[0] * nm + b0.x, 0.f), fmaxf(acc[1] * nm + b0.y, 0.f));
        ov.y = pack2(fmaxf(acc[2] * nm + b0.z, 0.f), fmaxf(acc[3] * nm + b0.w, 0.f));
        ov.z = pack2(fmaxf(acc[4] * nm + b1.x, 0.f), fmaxf(acc[5] * nm + b1.y, 0.f));
        ov.w = pack2(fmaxf(acc[6] * nm + b1.z, 0.f), fmaxf(acc[7] * nm + b1.w, 0.f));
        *(uint4*)&sA[g][lane * 8] = ov;
    }
    __syncthreads();
}

// ---------------- fused: aggregate + next-layer GEMM ------------------------

__global__ __launch_bounds__(256) void agg_gemm(const uint4* __restrict__ Abf,
                                                const int* __restrict__ csr,
                                                const unsigned* __restrict__ pd2,
                                                const int* __restrict__ perm,
                                                const float* __restrict__ bias,
                                                const unsigned short* __restrict__ Wt,
                                                unsigned short* __restrict__ outb, int N) {
    __shared__ unsigned short sA[16][SP];
    __shared__ int snode[16];
    __shared__ float snrm[16];
    gather_phase(Abf, csr, pd2, perm, bias, sA, snode, snrm, N);

    const int tid = threadIdx.x;
    const int wave = tid >> 6;
    const int l64 = tid & 63;
    const int m = l64 & 15;
    const int quad = l64 >> 4;

    f32x4 acc[2];
    acc[0] = (f32x4){0.f, 0.f, 0.f, 0.f};
    acc[1] = (f32x4){0.f, 0.f, 0.f, 0.f};

#pragma unroll
    for (int kt = 0; kt < 4; ++kt) {
        const int kof = kt * 32 + quad * 8;
        bf16x8 a = *(const bf16x8*)&sA[m][kof];
#pragma unroll
        for (int c2 = 0; c2 < 2; ++c2) {
            const int ct = wave * 2 + c2;
            bf16x8 b = *(const bf16x8*)(Wt + (ct * 16 + m) * DH + kof);
            acc[c2] = __builtin_amdgcn_mfma_f32_16x16x32_bf16(a, b, acc[c2], 0, 0, 0);
        }
    }

#pragma unroll
    for (int reg = 0; reg < 4; ++reg) {
        int idx = blockIdx.x * 16 + quad * 4 + reg;
        if (idx < N) {
            int r = snode[quad * 4 + reg];
            float s = snrm[quad * 4 + reg];
#pragma unroll
            for (int c2 = 0; c2 < 2; ++c2)
                outb[(size_t)r * DH + (wave * 2 + c2) * 16 + m] = f2bf(acc[c2][reg] * s);
        }
    }
}

// ---------------- fused: aggregate + head GEMM + log_softmax ----------------

__global__ __launch_bounds__(256) void agg_head(const uint4* __restrict__ Abf,
                                                const int* __restrict__ csr,
                                                const unsigned* __restrict__ pd2,
                                                const int* __restrict__ perm,
                                                const float* __restrict__ bias,
                                                const unsigned short* __restrict__ Wft,
                                                const float* __restrict__ bfh,
                                                float* __restrict__ out, int N) {
    __shared__ unsigned short sA[16][SP];
    __shared__ int snode[16];
    __shared__ float snrm[16];
    gather_phase(Abf, csr, pd2, perm, bias, sA, snode, snrm, N);

    const int tid = threadIdx.x;
    if (tid >= 64) return;                 // one wave does the 16x48 head
    const int m = tid & 15;
    const int quad = tid >> 4;

    f32x4 acc[3];
#pragma unroll
    for (int ct = 0; ct < 3; ++ct) acc[ct] = (f32x4){0.f, 0.f, 0.f, 0.f};

#pragma unroll
    for (int kt = 0; kt < 4; ++kt) {
        const int kof = kt * 32 + quad * 8;
        bf16x8 a = *(const bf16x8*)&sA[m][kof];
#pragma unroll
        for (int ct = 0; ct < 3; ++ct) {
            bf16x8 b = *(const bf16x8*)(Wft + (ct * 16 + m) * DH + kof);
            acc[ct] = __builtin_amdgcn_mfma_f32_16x16x32_bf16(a, b, acc[ct], 0, 0, 0);
        }
    }

    float bias0 = bfh[m];
    float bias1 = bfh[16 + m];
    float bias2 = bfh[32 + m];

#pragma unroll
    for (int reg = 0; reg < 4; ++reg) {
        float v0 = acc[0][reg] + bias0;
        float v1 = acc[1][reg] + bias1;
        float v2 = (m < 8) ? (acc[2][reg] + bias2) : -1e30f;
        float mx = fmaxf(fmaxf(v0, v1), v2);
#pragma unroll
        for (int dlt = 1; dlt < 16; dlt <<= 1) mx = fmaxf(mx, __shfl_xor(mx, dlt));
        float s = __expf(v0 - mx) + __expf(v1 - mx) + ((m < 8) ? __expf(v2 - mx) : 0.f);
#pragma unroll
        for (int dlt = 1; dlt < 16; dlt <<= 1) s += __shfl_xor(s, dlt);
        float ls = mx + __logf(s);
        int idx = blockIdx.x * 16 + quad * 4 + reg;
        if (idx < N) {
            int r = snode[quad * 4 + reg];
            out[(size_t)r * NC + m] = v0 - ls;
            out[(size_t)r * NC + 16 + m] = v1 - ls;
            if (m < 8) out[(size_t)r * NC + 32 + m] = v2 - ls;
        }
    }
}

// ---------------------------------------------------------------------------

extern "C" void kernel_launch(void* const* d_in, const int* in_sizes, int n_in,
                              void* d_out, int out_size, void* d_ws, size_t ws_size,
                              hipStream_t stream) {
    const float* x   = (const float*)d_in[0];
    const int*   ei  = (const int*)d_in[1];
    const float* W1  = (const float*)d_in[2];
    const float* b1  = (const float*)d_in[3];
    const float* W2  = (const float*)d_in[4];
    const float* b2  = (const float*)d_in[5];
    const float* W3  = (const float*)d_in[6];
    const float* b3  = (const float*)d_in[7];
    const float* Wp1 = (const float*)d_in[8];
    const float* bp1 = (const float*)d_in[9];
    const float* Wp2 = (const float*)d_in[10];
    const float* bp2 = (const float*)d_in[11];
    float* out = (float*)d_out;

    const int N = in_sizes[0] / DH;
    const int E = in_sizes[1] / 2;
    const int* src = ei;
    const int* dst = ei + E;
    const int NB = (N + BN - 1) / BN;

    // workspace carve (all 16B aligned)
    char* w = (char*)d_ws;
    unsigned short* Ab  = (unsigned short*)w; w += (size_t)N * DH * 2;
    unsigned short* Bb  = (unsigned short*)w; w += (size_t)N * DH * 2;
    int*      csr    = (int*)w;      w += (size_t)E * 4;
    unsigned* ebuf   = (unsigned*)w; w += (size_t)E * 4;
    unsigned* bcnt   = (unsigned*)w; w += MAXNB * 4;
    unsigned* cursor = (unsigned*)w; w += 16;
    unsigned* dh     = (unsigned*)w; w += 256 * 4;       // zeroed with bcnt
    unsigned* bbase  = (unsigned*)w; w += MAXNB * 4;
    unsigned* bpos   = (unsigned*)w; w += MAXNB * 4;
    unsigned* binpos = (unsigned*)w; w += 256 * 4;
    unsigned* nstart0= (unsigned*)w; w += 256 * 4;
    unsigned* estart = (unsigned*)w; w += 256 * 4;
    unsigned* cnt    = (unsigned*)w; w += (size_t)N * 4;
    float*    nrm    = (float*)w;    w += (size_t)N * 4;
    unsigned* offN   = (unsigned*)w; w += (size_t)N * 4;
    unsigned* pd2    = (unsigned*)w; w += (size_t)((N + 31) & ~31) * 4;
    int*      perm   = (int*)w;      w += (size_t)((N + 31) & ~31) * 4;
    unsigned short* Wt  = (unsigned short*)w; w += 3 * DH * DH * 2;
    unsigned short* Wft = (unsigned short*)w; w += 48 * DH * 2;
    float*    bfh    = (float*)w;    w += 64 * 4;

    const int gC = (E + CH - 1) / CH;
    const int gN = (N + 255) / 256;

    hipMemsetAsync(bcnt, 0, MAXNB * 4 + 16 + 256 * 4, stream);   // bcnt+cursor+dh
    bucket_hist   <<<gC, 256, 0, stream>>>(dst, E, bcnt);
    bucket_alloc  <<<(NB + 255) / 256, 256, 0, stream>>>(bcnt, bbase, bpos, cursor, NB);
    bucket_scatter<<<gC, 256, 0, stream>>>(src, dst, E, bpos, ebuf);
    bucket_deg    <<<NB, 256, 0, stream>>>(ebuf, bbase, bcnt, cnt, nrm, dh, N);
    deg_scan      <<<1, 256, 0, stream>>>(dh, binpos, nstart0, estart);
    deg_scatter   <<<gN, 256, 0, stream>>>(cnt, N, binpos, nstart0, estart, perm, pd2, offN);
    bucket_fill   <<<NB, 256, 0, stream>>>(ebuf, bbase, bcnt, offN, csr, N);
    prep_w<<<(3 * DH * DH + 48 * DH + 48 + 255) / 256, 256, 0, stream>>>(
        W1, W2, W3, Wp1, bp1, Wp2, bp2, Wt, Wft, bfh);

    const int gG = (N + 127) / 128;
    const int gF = (N + 15) / 16;

    gemm_mfma_f32<<<gG, 256, 0, stream>>>(x, Wt, nrm, Ab, N);
    agg_gemm<<<gF, 256, 0, stream>>>((const uint4*)Ab, csr, pd2, perm, b1,
                                     Wt + DH * DH, Bb, N);
    agg_gemm<<<gF, 256, 0, stream>>>((const uint4*)Bb, csr, pd2, perm, b2,
                                     Wt + 2 * DH * DH, Ab, N);
    agg_head<<<gF, 256, 0, stream>>>((const uint4*)Ab, csr, pd2, perm, b3,
                                     Wft, bfh, out, N);
}